// Round 17
// baseline (714.928 us; speedup 1.0000x reference)
//
#include <hip/hip_runtime.h>
#include <hip/hip_bf16.h>

#define DIM 256
#define HEADS 4
#define NEG_SLOPE 0.01f
#define ROWS_REG 6

typedef unsigned short u16;
typedef __attribute__((ext_vector_type(8))) short short8;
typedef __attribute__((ext_vector_type(4))) float f32x4;

// ---- bf16 helpers ----
__device__ __forceinline__ u16 f2bf(float f) {           // RTN-even
    unsigned u = __float_as_uint(f);
    unsigned r = (u + 0x7fffu + ((u >> 16) & 1u)) >> 16;
    return (u16)r;
}
__device__ __forceinline__ unsigned cvt2(float a, float b) {   // native v_cvt_pk path
    __hip_bfloat162 h = __float22bfloat162_rn(make_float2(a, b));
    unsigned u;
    __builtin_memcpy(&u, &h, 4);
    return u;
}

// K0a: transpose w_q (k-major fp32) -> BThi (n-major bf16, RTN)
__global__ __launch_bounds__(256) void prepb_kernel(const float* __restrict__ B,
                                                    u16* __restrict__ BThi) {
    int k = blockIdx.x;
    int n = threadIdx.x;
    BThi[n * 256 + k] = f2bf(B[k * 256 + n]);
}

// K0b: wg[k][h] = sum_{d<64} w_q[k][h*64+d] * weight[h][64+d]   (256x4 fp32)
__global__ __launch_bounds__(256) void prepwg_kernel(const float* __restrict__ wq,
                                                     const float* __restrict__ weight,
                                                     float* __restrict__ wg) {
    int k = threadIdx.x;
#pragma unroll
    for (int h = 0; h < 4; ++h) {
        float s = 0.f;
        for (int d = 0; d < 64; ++d)
            s = fmaf(wq[k * 256 + h * 64 + d], weight[h * 128 + 64 + d], s);
        wg[k * 4 + h] = s;
    }
}

// K1: beta[j,h] = sum_{d<64} x_edge[j, h*64+d] * weight[h, d]
__global__ __launch_bounds__(256) void beta_kernel(const float* __restrict__ xe,
                                                   const float* __restrict__ weight,
                                                   float* __restrict__ beta, int NE) {
    int wid = blockIdx.x * 4 + (threadIdx.x >> 6);
    if (wid >= NE) return;
    int lane = threadIdx.x & 63;
    int h = lane >> 4;
    float4 v = *reinterpret_cast<const float4*>(xe + (size_t)wid * DIM + lane * 4);
    float4 w = *reinterpret_cast<const float4*>(weight + h * 128 + (lane & 15) * 4);
    float p = v.x * w.x + v.y * w.y + v.z * w.z + v.w * w.w;
    p += __shfl_xor(p, 1);
    p += __shfl_xor(p, 2);
    p += __shfl_xor(p, 4);
    p += __shfl_xor(p, 8);
    if ((lane & 15) == 0) beta[(size_t)wid * 4 + h] = p;
}

// K2: histogram of edge ids
__global__ __launch_bounds__(256) void count_kernel(const int* __restrict__ eids,
                                                    unsigned* __restrict__ counts, int NQ) {
    int e = blockIdx.x * blockDim.x + threadIdx.x;
    if (e >= NQ) return;
    atomicAdd(&counts[eids[e]], 1u);
}

// ---- CSR build ----
__global__ __launch_bounds__(256) void scan1_kernel(const unsigned* __restrict__ counts,
                                                    unsigned* __restrict__ offs,
                                                    unsigned* __restrict__ blocksums, int NE) {
    __shared__ unsigned s[256];
    int t = threadIdx.x;
    int base = blockIdx.x * 1024 + t * 4;
    unsigned v[4], sum = 0;
#pragma unroll
    for (int i = 0; i < 4; ++i) {
        v[i] = (base + i < NE) ? counts[base + i] : 0u;
        sum += v[i];
    }
    s[t] = sum;
    __syncthreads();
    for (int off = 1; off < 256; off <<= 1) {
        unsigned y = (t >= off) ? s[t - off] : 0u;
        __syncthreads();
        s[t] += y;
        __syncthreads();
    }
    unsigned excl = s[t] - sum;
#pragma unroll
    for (int i = 0; i < 4; ++i) {
        if (base + i < NE) offs[base + i] = excl;
        excl += v[i];
    }
    if (t == 255) blocksums[blockIdx.x] = s[255];
}

__global__ __launch_bounds__(256) void scan2_kernel(unsigned* __restrict__ blocksums, int NB) {
    __shared__ unsigned s[256];
    int t = threadIdx.x;
    unsigned v = (t < NB) ? blocksums[t] : 0u;
    s[t] = v;
    __syncthreads();
    for (int off = 1; off < 256; off <<= 1) {
        unsigned y = (t >= off) ? s[t - off] : 0u;
        __syncthreads();
        s[t] += y;
        __syncthreads();
    }
    if (t < NB) blocksums[t] = s[t] - v;
}

__global__ __launch_bounds__(256) void scan3_kernel(unsigned* __restrict__ offs,
                                                    const unsigned* __restrict__ blocksums,
                                                    unsigned* __restrict__ cursor, int NE) {
    int t = threadIdx.x;
    int base = blockIdx.x * 1024 + t * 4;
    unsigned add = blocksums[blockIdx.x];
#pragma unroll
    for (int i = 0; i < 4; ++i) {
        if (base + i < NE) {
            unsigned o = offs[base + i] + add;
            offs[base + i] = o;
            cursor[base + i] = o;
        }
    }
}

__global__ __launch_bounds__(256) void fill_kernel(const int* __restrict__ eids,
                                                   unsigned* __restrict__ cursor,
                                                   int* __restrict__ qlist, int NQ) {
    int e = blockIdx.x * blockDim.x + threadIdx.x;
    if (e >= NQ) return;
    int j = eids[e];
    unsigned pos = atomicAdd(&cursor[j], 1u);
    qlist[pos] = e;
}

// K5: FULLY fused softmax + aggregate + GEMM. Block = 512 threads = 8 waves = 16 edges.
// Phase A (wave-per-edge, 2 edges/wave): load the segment's x_q rows ONCE
//   (<=ROWS_REG kept in registers; overflow rows re-read, L2/L3-hot), compute
//   gamma per row in-wave (16 FMAs + 6-level shfl butterfly -> all lanes hold
//   gamma), ex = exp(leaky(beta+gamma)), segment sum in registers (no atomics),
//   normalize, aggregate. Write bf16 LDS tile with r16's proven swizzle.
// Phase B (r16 verbatim): wave w -> head h=w>>1, col-pair gp=w&1; A from LDS,
//   B direct from BThi (L2). 16 MFMAs -> out.
__global__ __launch_bounds__(512, 4) void fused_kernel(const float* __restrict__ xq,
                                                       const u16* __restrict__ BThi,
                                                       const float* __restrict__ wg,
                                                       const float* __restrict__ beta,
                                                       const unsigned* __restrict__ offs,
                                                       const unsigned* __restrict__ counts,
                                                       const int* __restrict__ qlist,
                                                       float* __restrict__ out, int NE) {
    __shared__ u16 agg_s[64 * 256];   // 32 KB: [row = e_loc*4 + h][k]

    const int t = threadIdx.x;
    const int w = t >> 6;            // wave 0..7
    const int lane = t & 63;

    // ---------- Phase A ----------
#pragma unroll 1
    for (int e2 = 0; e2 < 2; ++e2) {
        const int e_loc = w * 2 + e2;               // 0..15
        const long j = (long)blockIdx.x * 16 + e_loc;
        f32x4 a0 = (f32x4){0.f, 0.f, 0.f, 0.f};
        f32x4 a1 = a0, a2 = a0, a3 = a0;            // per-head aggregates (4 cols each)
        if (j < NE) {
            const unsigned beg = offs[j];
            const unsigned n = counts[j];
            const unsigned nn = n < ROWS_REG ? n : ROWS_REG;
            const float4 b4 = *reinterpret_cast<const float4*>(beta + (size_t)j * 4);
            const float* xcol = xq + lane * 4;

            // gamma+ex for one row held in xv (all lanes end with same ex)
            auto gamma_ex = [&](float4 xv) -> float4 {
                float4 p = make_float4(0.f, 0.f, 0.f, 0.f);
                const float xs[4] = {xv.x, xv.y, xv.z, xv.w};
#pragma unroll
                for (int c = 0; c < 4; ++c) {
                    float4 wr = *reinterpret_cast<const float4*>(wg + (lane * 4 + c) * 4);
                    p.x = fmaf(xs[c], wr.x, p.x);
                    p.y = fmaf(xs[c], wr.y, p.y);
                    p.z = fmaf(xs[c], wr.z, p.z);
                    p.w = fmaf(xs[c], wr.w, p.w);
                }
#pragma unroll
                for (int d = 1; d < 64; d <<= 1) {
                    p.x += __shfl_xor(p.x, d);
                    p.y += __shfl_xor(p.y, d);
                    p.z += __shfl_xor(p.z, d);
                    p.w += __shfl_xor(p.w, d);
                }
                float l0 = b4.x + p.x, l1 = b4.y + p.y, l2 = b4.z + p.z, l3 = b4.w + p.w;
                l0 = l0 > 0.f ? l0 : NEG_SLOPE * l0;
                l1 = l1 > 0.f ? l1 : NEG_SLOPE * l1;
                l2 = l2 > 0.f ? l2 : NEG_SLOPE * l2;
                l3 = l3 > 0.f ? l3 : NEG_SLOPE * l3;
                return make_float4(__expf(l0), __expf(l1), __expf(l2), __expf(l3));
            };

            // load register-resident rows (parallel, uniform branches)
            float4 xr[ROWS_REG];
            float4 exr[ROWS_REG];
#pragma unroll
            for (int i = 0; i < ROWS_REG; ++i)
                if ((unsigned)i < nn) {
                    int q = qlist[beg + i];
                    xr[i] = *reinterpret_cast<const float4*>(xcol + (size_t)q * DIM);
                }
            float4 ssum = make_float4(0.f, 0.f, 0.f, 0.f);
#pragma unroll
            for (int i = 0; i < ROWS_REG; ++i)
                if ((unsigned)i < nn) {
                    float4 e = gamma_ex(xr[i]);
                    exr[i] = e;
                    ssum.x += e.x; ssum.y += e.y; ssum.z += e.z; ssum.w += e.w;
                }
            // overflow pass 1 (rare): sum ex of remaining rows
            for (unsigned i = ROWS_REG; i < n; ++i) {
                int q = qlist[beg + i];
                float4 xv = *reinterpret_cast<const float4*>(xcol + (size_t)q * DIM);
                float4 e = gamma_ex(xv);
                ssum.x += e.x; ssum.y += e.y; ssum.z += e.z; ssum.w += e.w;
            }
            const float inv0 = 1.f / (ssum.x + 1e-16f);
            const float inv1 = 1.f / (ssum.y + 1e-16f);
            const float inv2 = 1.f / (ssum.z + 1e-16f);
            const float inv3 = 1.f / (ssum.w + 1e-16f);
            // aggregate register rows
#pragma unroll
            for (int i = 0; i < ROWS_REG; ++i)
                if ((unsigned)i < nn) {
                    f32x4 xvv = {xr[i].x, xr[i].y, xr[i].z, xr[i].w};
                    a0 += (exr[i].x * inv0) * xvv;
                    a1 += (exr[i].y * inv1) * xvv;
                    a2 += (exr[i].z * inv2) * xvv;
                    a3 += (exr[i].w * inv3) * xvv;
                }
            // overflow pass 2 (rare): re-read (L2/L3-hot) + recompute ex
            for (unsigned i = ROWS_REG; i < n; ++i) {
                int q = qlist[beg + i];
                float4 xv = *reinterpret_cast<const float4*>(xcol + (size_t)q * DIM);
                float4 e = gamma_ex(xv);
                f32x4 xvv = {xv.x, xv.y, xv.z, xv.w};
                a0 += (e.x * inv0) * xvv;
                a1 += (e.y * inv1) * xvv;
                a2 += (e.z * inv2) * xvv;
                a3 += (e.w * inv3) * xvv;
            }
        }
        // write 4 rows; r16 swizzle: phys_chunk = (lane>>1) ^ (row & 7)
        const int halfsel = (lane & 1) * 4;
        f32x4 accs[4] = {a0, a1, a2, a3};
#pragma unroll
        for (int h = 0; h < 4; ++h) {
            int row = e_loc * 4 + h;
            int chunk = (lane >> 1) ^ (row & 7);
            uint2 wv = make_uint2(cvt2(accs[h][0], accs[h][1]), cvt2(accs[h][2], accs[h][3]));
            *reinterpret_cast<uint2*>(&agg_s[row * 256 + chunk * 8 + halfsel]) = wv;
        }
    }
    __syncthreads();

    // ---------- Phase B: MFMA (r16 verbatim) ----------
    const int h = w >> 1;
    const int gp = w & 1;
    const int lr = lane & 15;
    const int kg = lane >> 4;
    const int rowA = lr * 4 + h;                  // edge lr, head h
    const u16* bptr0 = BThi + (h * 64 + gp * 32 + lr) * 256 + kg * 8;
    const u16* bptr1 = bptr0 + 16 * 256;

    f32x4 cc0 = (f32x4){0.f, 0.f, 0.f, 0.f};
    f32x4 cc1 = cc0;
#pragma unroll
    for (int s = 0; s < 8; ++s) {
        int phys = (s * 4 + kg) ^ (rowA & 7);
        short8 ah = *reinterpret_cast<const short8*>(&agg_s[rowA * 256 + phys * 8]);
        short8 b0 = *reinterpret_cast<const short8*>(bptr0 + s * 32);
        short8 b1 = *reinterpret_cast<const short8*>(bptr1 + s * 32);
        cc0 = __builtin_amdgcn_mfma_f32_16x16x32_bf16(ah, b0, cc0, 0, 0, 0);
        cc1 = __builtin_amdgcn_mfma_f32_16x16x32_bf16(ah, b1, cc1, 0, 0, 0);
    }
#pragma unroll
    for (int r = 0; r < 4; ++r) {
        long jj = (long)blockIdx.x * 16 + kg * 4 + r;
        if (jj < NE) {
            float* orow = out + jj * DIM + h * 64 + gp * 32 + lr;
            orow[0]  = cc0[r];
            orow[16] = cc1[r];
        }
    }
}

extern "C" void kernel_launch(void* const* d_in, const int* in_sizes, int n_in,
                              void* d_out, int out_size, void* d_ws, size_t ws_size,
                              hipStream_t stream) {
    (void)n_in; (void)out_size; (void)ws_size;
    const float* x_q    = (const float*)d_in[0];
    const float* x_edge = (const float*)d_in[1];
    const float* w_q    = (const float*)d_in[2];
    const float* weight = (const float*)d_in[3];
    const int*   eids   = (const int*)d_in[4];
    const int NQ = in_sizes[0] / DIM;   // 500000
    const int NE = in_sizes[1] / DIM;   // 250000
    float* out = (float*)d_out;

    // workspace layout
    float*    beta      = (float*)d_ws;                         // NE*4
    unsigned* counts    = (unsigned*)(beta + (size_t)NE * 4);   // NE
    unsigned* offs      = counts + NE;                          // NE
    unsigned* cursor    = offs + NE;                            // NE
    int*      qlist     = (int*)(cursor + NE);                  // NQ
    unsigned* blocksums = (unsigned*)(qlist + NQ);              // 256
    u16*      BThi      = (u16*)(blocksums + 256);              // 256*256
    float*    wg        = (float*)(BThi + 256 * 256);           // 256*4

    const int NB = (NE + 1023) / 1024;

    hipMemsetAsync(counts, 0, (size_t)NE * sizeof(unsigned), stream);

    prepb_kernel<<<256, 256, 0, stream>>>(w_q, BThi);
    prepwg_kernel<<<1, 256, 0, stream>>>(w_q, weight, wg);
    beta_kernel<<<(NE + 3) / 4, 256, 0, stream>>>(x_edge, weight, beta, NE);
    count_kernel<<<(NQ + 255) / 256, 256, 0, stream>>>(eids, counts, NQ);
    scan1_kernel<<<NB, 256, 0, stream>>>(counts, offs, blocksums, NE);
    scan2_kernel<<<1, 256, 0, stream>>>(blocksums, NB);
    scan3_kernel<<<NB, 256, 0, stream>>>(offs, blocksums, cursor, NE);
    fill_kernel<<<(NQ + 255) / 256, 256, 0, stream>>>(eids, cursor, qlist, NQ);
    fused_kernel<<<(NE + 15) / 16, 512, 0, stream>>>(x_q, BThi, wg, beta, offs, counts,
                                                     qlist, out, NE);
}

// Round 18
// 574.091 us; speedup vs baseline: 1.2453x; 1.2453x over previous
//
#include <hip/hip_runtime.h>
#include <hip/hip_bf16.h>

#define DIM 256
#define HEADS 4
#define NEG_SLOPE 0.01f

typedef unsigned short u16;
typedef __attribute__((ext_vector_type(8))) short short8;
typedef __attribute__((ext_vector_type(4))) float f32x4;
typedef __attribute__((ext_vector_type(4))) unsigned short u16x4;

// ---- bf16 helpers ----
__device__ __forceinline__ u16 f2bf(float f) {           // RTN-even
    unsigned u = __float_as_uint(f);
    unsigned r = (u + 0x7fffu + ((u >> 16) & 1u)) >> 16;
    return (u16)r;
}
__device__ __forceinline__ float bf2f(u16 h) {
    return __uint_as_float(((unsigned)h) << 16);
}
__device__ __forceinline__ unsigned cvt2(float a, float b) {   // native v_cvt_pk path
    __hip_bfloat162 h = __float22bfloat162_rn(make_float2(a, b));
    unsigned u;
    __builtin_memcpy(&u, &h, 4);
    return u;
}

// K0: transpose w_q (k-major fp32) -> BThi (n-major bf16, RTN)
__global__ __launch_bounds__(256) void prepb_kernel(const float* __restrict__ B,
                                                    u16* __restrict__ BThi) {
    int k = blockIdx.x;
    int n = threadIdx.x;
    BThi[n * 256 + k] = f2bf(B[k * 256 + n]);
}

// K1: beta[j,h] = sum_{d<64} x_edge[j, h*64+d] * weight[h, d]
__global__ __launch_bounds__(256) void beta_kernel(const float* __restrict__ xe,
                                                   const float* __restrict__ weight,
                                                   float* __restrict__ beta, int NE) {
    int wid = blockIdx.x * 4 + (threadIdx.x >> 6);
    if (wid >= NE) return;
    int lane = threadIdx.x & 63;
    int h = lane >> 4;
    float4 v = *reinterpret_cast<const float4*>(xe + (size_t)wid * DIM + lane * 4);
    float4 w = *reinterpret_cast<const float4*>(weight + h * 128 + (lane & 15) * 4);
    float p = v.x * w.x + v.y * w.y + v.z * w.z + v.w * w.w;
    p += __shfl_xor(p, 1);
    p += __shfl_xor(p, 2);
    p += __shfl_xor(p, 4);
    p += __shfl_xor(p, 8);
    if ((lane & 15) == 0) beta[(size_t)wid * 4 + h] = p;
}

// K2: xq = x_q @ w_q via bf16 MFMA, BK=128 (2 k-steps -> 2 drain windows).
// A: 8xfloat4 burst per thread -> convert -> single-buffer LDS [64][128] bf16,
//    16B-chunk swizzle pc = lc ^ (row & 15).
// B: direct global->reg fragments (128 KB bf16, L2-resident).
// Fused epilogue: gamma -> logit -> ex -> exv/segsum/counts.
// 256 threads = 4 waves, one per 64-col head group. BM=64, BN=256.
__global__ __launch_bounds__(256, 3) void gemm_fused_kernel(const float* __restrict__ A,
                                                            const u16* __restrict__ BThi,
                                                            const float* __restrict__ weight,
                                                            const float* __restrict__ beta,
                                                            const int* __restrict__ eids,
                                                            u16* __restrict__ xq_out,
                                                            float* __restrict__ exv,
                                                            float* __restrict__ segsum,
                                                            unsigned* __restrict__ counts,
                                                            int NQ) {
    __shared__ u16 A_s[64 * 128];   // 16 KB

    const int t = threadIdx.x;
    const int lane = t & 63;
    const int wc = t >> 6;         // wave = head / 64-col group
    const int lr = lane & 15;
    const int kg = lane >> 4;
    const long brow = (long)blockIdx.x * 64;

    // staging: thread t covers row = t>>2, 32 floats at (t&3)*32
    const int s_row = t >> 2, s_kq = t & 3;
    const float* aptr;
    {
        long sg = brow + s_row;
        if (sg >= NQ) sg = NQ - 1;
        aptr = A + sg * DIM + s_kq * 32;
    }

    // B fragment pointers (direct from L2)
    const u16* brows[4];
#pragma unroll
    for (int n = 0; n < 4; ++n)
        brows[n] = BThi + (wc * 64 + n * 16 + lr) * 256 + kg * 8;

    f32x4 acc[4][4];
#pragma unroll
    for (int m = 0; m < 4; ++m)
#pragma unroll
        for (int n = 0; n < 4; ++n) acc[m][n] = (f32x4){0.f, 0.f, 0.f, 0.f};

#pragma unroll 1
    for (int k0 = 0; k0 < DIM; k0 += 128) {
        // burst-load this thread's 128 B of A
        float4 ar[8];
#pragma unroll
        for (int i = 0; i < 8; ++i)
            ar[i] = *reinterpret_cast<const float4*>(aptr + k0 + i * 4);
        if (k0) __syncthreads();   // all waves done reading previous tile
        // convert + write 4 swizzled 16B chunks
#pragma unroll
        for (int i = 0; i < 4; ++i) {
            uint4 wv;
            wv.x = cvt2(ar[2 * i].x, ar[2 * i].y);
            wv.y = cvt2(ar[2 * i].z, ar[2 * i].w);
            wv.z = cvt2(ar[2 * i + 1].x, ar[2 * i + 1].y);
            wv.w = cvt2(ar[2 * i + 1].z, ar[2 * i + 1].w);
            int lc = s_kq * 4 + i;
            int pc = lc ^ (s_row & 15);
            *reinterpret_cast<uint4*>(&A_s[s_row * 128 + pc * 8]) = wv;
        }
        __syncthreads();
        // compute 4 k-subtiles of 32
#pragma unroll
        for (int s = 0; s < 4; ++s) {
            short8 bh[4];
#pragma unroll
            for (int n = 0; n < 4; ++n)
                bh[n] = *reinterpret_cast<const short8*>(brows[n] + k0 + s * 32);
#pragma unroll
            for (int m = 0; m < 4; ++m) {
                int rr = m * 16 + lr;
                int pc = (s * 4 + kg) ^ (rr & 15);
                short8 ah = *reinterpret_cast<const short8*>(&A_s[rr * 128 + pc * 8]);
#pragma unroll
                for (int n = 0; n < 4; ++n)
                    acc[m][n] = __builtin_amdgcn_mfma_f32_16x16x32_bf16(ah, bh[n], acc[m][n], 0, 0, 0);
            }
        }
    }

    // epilogue: bf16 xq stores + per-head gamma -> ex -> segsum/counts
    float wv[4];
#pragma unroll
    for (int n = 0; n < 4; ++n) wv[n] = weight[wc * 128 + 64 + n * 16 + lr];

#pragma unroll
    for (int m = 0; m < 4; ++m) {
#pragma unroll
        for (int r = 0; r < 4; ++r) {
            long row = brow + m * 16 + kg * 4 + r;
            bool ok = row < NQ;
            float p = 0.f;
#pragma unroll
            for (int n = 0; n < 4; ++n) {
                float v = acc[m][n][r];
                if (ok) xq_out[row * DIM + wc * 64 + n * 16 + lr] = f2bf(v);
                p = fmaf(v, wv[n], p);
            }
            p += __shfl_xor(p, 1);
            p += __shfl_xor(p, 2);
            p += __shfl_xor(p, 4);
            p += __shfl_xor(p, 8);
            if (ok && lr == 0) {
                int j = eids[row];
                float l = beta[(size_t)j * 4 + wc] + p;
                l = l > 0.f ? l : NEG_SLOPE * l;
                float e = __expf(l);
                exv[row * 4 + wc] = e;
                atomicAdd(&segsum[(size_t)j * 4 + wc], e);
                if (wc == 0) atomicAdd(&counts[j], 1u);
            }
        }
    }
}

// ---- CSR build ----
__global__ __launch_bounds__(256) void scan1_kernel(const unsigned* __restrict__ counts,
                                                    unsigned* __restrict__ offs,
                                                    unsigned* __restrict__ blocksums, int NE) {
    __shared__ unsigned s[256];
    int t = threadIdx.x;
    int base = blockIdx.x * 1024 + t * 4;
    unsigned v[4], sum = 0;
#pragma unroll
    for (int i = 0; i < 4; ++i) {
        v[i] = (base + i < NE) ? counts[base + i] : 0u;
        sum += v[i];
    }
    s[t] = sum;
    __syncthreads();
    for (int off = 1; off < 256; off <<= 1) {
        unsigned y = (t >= off) ? s[t - off] : 0u;
        __syncthreads();
        s[t] += y;
        __syncthreads();
    }
    unsigned excl = s[t] - sum;
#pragma unroll
    for (int i = 0; i < 4; ++i) {
        if (base + i < NE) offs[base + i] = excl;
        excl += v[i];
    }
    if (t == 255) blocksums[blockIdx.x] = s[255];
}

__global__ __launch_bounds__(256) void scan2_kernel(unsigned* __restrict__ blocksums, int NB) {
    __shared__ unsigned s[256];
    int t = threadIdx.x;
    unsigned v = (t < NB) ? blocksums[t] : 0u;
    s[t] = v;
    __syncthreads();
    for (int off = 1; off < 256; off <<= 1) {
        unsigned y = (t >= off) ? s[t - off] : 0u;
        __syncthreads();
        s[t] += y;
        __syncthreads();
    }
    if (t < NB) blocksums[t] = s[t] - v;
}

__global__ __launch_bounds__(256) void scan3_kernel(unsigned* __restrict__ offs,
                                                    const unsigned* __restrict__ blocksums,
                                                    unsigned* __restrict__ cursor, int NE) {
    int t = threadIdx.x;
    int base = blockIdx.x * 1024 + t * 4;
    unsigned add = blocksums[blockIdx.x];
#pragma unroll
    for (int i = 0; i < 4; ++i) {
        if (base + i < NE) {
            unsigned o = offs[base + i] + add;
            offs[base + i] = o;
            cursor[base + i] = o;
        }
    }
}

__global__ __launch_bounds__(256) void fill_kernel(const int* __restrict__ eids,
                                                   unsigned* __restrict__ cursor,
                                                   int* __restrict__ qlist, int NQ) {
    int e = blockIdx.x * blockDim.x + threadIdx.x;
    if (e >= NQ) return;
    int j = eids[e];
    unsigned pos = atomicAdd(&cursor[j], 1u);
    qlist[pos] = e;
}

// gather: out[j,:] = sum_{q in seg(j)} (ex[q,h]/(segsum[j,h]+eps)) * xq_bf16[q,:]
__global__ __launch_bounds__(256) void gather_kernel(const float* __restrict__ exv,
                                                     const float* __restrict__ segsum,
                                                     const unsigned* __restrict__ offs,
                                                     const unsigned* __restrict__ counts,
                                                     const int* __restrict__ qlist,
                                                     const u16* __restrict__ xq,
                                                     float* __restrict__ out, int NE) {
    int j = blockIdx.x * 4 + (threadIdx.x >> 6);
    if (j >= NE) return;
    int lane = threadIdx.x & 63;
    int h = lane >> 4;
    unsigned beg = offs[j];
    unsigned n = counts[j];
    float inv = 1.0f / (segsum[(size_t)j * 4 + h] + 1e-16f);
    float4 a0 = make_float4(0.f, 0.f, 0.f, 0.f);
    float4 a1 = make_float4(0.f, 0.f, 0.f, 0.f);
    unsigned i = 0;
    for (; i + 2 <= n; i += 2) {
        int q0 = qlist[beg + i];
        int q1 = qlist[beg + i + 1];
        float w0 = exv[(size_t)q0 * 4 + h] * inv;
        float w1 = exv[(size_t)q1 * 4 + h] * inv;
        u16x4 v0 = *reinterpret_cast<const u16x4*>(xq + (size_t)q0 * DIM + lane * 4);
        u16x4 v1 = *reinterpret_cast<const u16x4*>(xq + (size_t)q1 * DIM + lane * 4);
        a0.x = fmaf(w0, bf2f(v0.x), a0.x); a1.x = fmaf(w1, bf2f(v1.x), a1.x);
        a0.y = fmaf(w0, bf2f(v0.y), a0.y); a1.y = fmaf(w1, bf2f(v1.y), a1.y);
        a0.z = fmaf(w0, bf2f(v0.z), a0.z); a1.z = fmaf(w1, bf2f(v1.z), a1.z);
        a0.w = fmaf(w0, bf2f(v0.w), a0.w); a1.w = fmaf(w1, bf2f(v1.w), a1.w);
    }
    if (i < n) {
        int q0 = qlist[beg + i];
        float w0 = exv[(size_t)q0 * 4 + h] * inv;
        u16x4 v0 = *reinterpret_cast<const u16x4*>(xq + (size_t)q0 * DIM + lane * 4);
        a0.x = fmaf(w0, bf2f(v0.x), a0.x);
        a0.y = fmaf(w0, bf2f(v0.y), a0.y);
        a0.z = fmaf(w0, bf2f(v0.z), a0.z);
        a0.w = fmaf(w0, bf2f(v0.w), a0.w);
    }
    float4 acc = make_float4(a0.x + a1.x, a0.y + a1.y, a0.z + a1.z, a0.w + a1.w);
    *reinterpret_cast<float4*>(out + (size_t)j * DIM + lane * 4) = acc;
}

extern "C" void kernel_launch(void* const* d_in, const int* in_sizes, int n_in,
                              void* d_out, int out_size, void* d_ws, size_t ws_size,
                              hipStream_t stream) {
    (void)n_in; (void)out_size; (void)ws_size;
    const float* x_q    = (const float*)d_in[0];
    const float* x_edge = (const float*)d_in[1];
    const float* w_q    = (const float*)d_in[2];
    const float* weight = (const float*)d_in[3];
    const int*   eids   = (const int*)d_in[4];
    const int NQ = in_sizes[0] / DIM;   // 500000
    const int NE = in_sizes[1] / DIM;   // 250000
    float* out = (float*)d_out;

    // workspace layout
    u16*      xq        = (u16*)d_ws;                           // NQ*256 bf16
    float*    exv       = (float*)(xq + (size_t)NQ * DIM);      // NQ*4
    float*    beta      = exv + (size_t)NQ * 4;                 // NE*4
    float*    segsum    = beta + (size_t)NE * 4;                // NE*4
    unsigned* counts    = (unsigned*)(segsum + (size_t)NE * 4); // NE
    unsigned* offs      = counts + NE;                          // NE
    unsigned* cursor    = offs + NE;                            // NE
    int*      qlist     = (int*)(cursor + NE);                  // NQ
    unsigned* blocksums = (unsigned*)(qlist + NQ);              // 256
    u16*      BThi      = (u16*)(blocksums + 256);              // 256*256

    const int NB = (NE + 1023) / 1024;

    hipMemsetAsync(segsum, 0, (size_t)NE * 4 * sizeof(float), stream);
    hipMemsetAsync(counts, 0, (size_t)NE * sizeof(unsigned), stream);

    prepb_kernel<<<256, 256, 0, stream>>>(w_q, BThi);
    beta_kernel<<<(NE + 3) / 4, 256, 0, stream>>>(x_edge, weight, beta, NE);
    gemm_fused_kernel<<<(NQ + 63) / 64, 256, 0, stream>>>(x_q, BThi, weight, beta, eids,
                                                          xq, exv, segsum, counts, NQ);
    scan1_kernel<<<NB, 256, 0, stream>>>(counts, offs, blocksums, NE);
    scan2_kernel<<<1, 256, 0, stream>>>(blocksums, NB);
    scan3_kernel<<<NB, 256, 0, stream>>>(offs, blocksums, cursor, NE);
    fill_kernel<<<(NQ + 255) / 256, 256, 0, stream>>>(eids, cursor, qlist, NQ);
    gather_kernel<<<(NE + 3) / 4, 256, 0, stream>>>(exv, segsum, offs, counts, qlist, xq, out, NE);
}